// Round 15
// baseline (374.898 us; speedup 1.0000x reference)
//
#include <hip/hip_runtime.h>
#include <math.h>

// Problem constants
#define BB 8
#define LL 512
#define UU 24
#define DD 1024
#define HH 16
#define DH 64
#define TT 72
#define CSKN 1024
#define NVOCAB 54945

typedef __attribute__((ext_vector_type(8))) short bf16x8;
typedef __attribute__((ext_vector_type(4))) float f32x4;

__device__ inline unsigned short f2b(float x) {
    unsigned u = __float_as_uint(x);
    unsigned r = u + 0x7FFFu + ((u >> 16) & 1u);
    return (unsigned short)(r >> 16);
}
__device__ inline unsigned pack2(float lo, float hi) {
    return (unsigned)f2b(lo) | ((unsigned)f2b(hi) << 16);
}
__device__ inline void dec8(uint2 c, float* cr) {
    cr[0] = (float)( c.x        & 0xff); cr[1] = (float)((c.x >>  8) & 0xff);
    cr[2] = (float)((c.x >> 16) & 0xff); cr[3] = (float)((c.x >> 24) & 0xff);
    cr[4] = (float)( c.y        & 0xff); cr[5] = (float)((c.y >>  8) & 0xff);
    cr[6] = (float)((c.y >> 16) & 0xff); cr[7] = (float)((c.y >> 24) & 0xff);
}

// ---------------------------------------------------------------------------
// Merged: gather cls (blocks 0..191) + batchnorm (blocks 192..959)
__global__ __launch_bounds__(256) void k_gather_bn(const float* __restrict__ hidden,
        const int* __restrict__ idx, float* __restrict__ sem_cls, float* __restrict__ trans_in,
        const float* __restrict__ x, const float* __restrict__ g,
        const float* __restrict__ be, const float* __restrict__ mu,
        const float* __restrict__ var, float* __restrict__ y)
{
    int bid = blockIdx.x;
    if (bid < BB*UU) {
        int b = bid / UU, u = bid % UU;
        int row = idx[b*UU + u];
        const float* src = hidden + ((size_t)(b*LL + row))*DD;
        float* d0 = trans_in + ((size_t)(b*TT + 3*u))*DD;
        float* sc = sem_cls + ((size_t)(b*UU + u))*DD;
        for (int d = threadIdx.x; d < DD; d += 256) {
            float v = src[d];
            sc[d] = v;
            d0[d] = v; d0[DD + d] = v; d0[2*DD + d] = v;
        }
    } else {
        int i = (bid - BB*UU)*256 + threadIdx.x;
        int n = BB*UU*CSKN;
        if (i < n) {
            int c = i % CSKN;
            y[i] = (x[i] - mu[c]) * (1.0f/sqrtf(var[c] + 1e-5f)) * g[c] + be[c];
        }
    }
}

// ---------------------------------------------------------------------------
// MFMA bf16 GEMM, 64x64 tile, BK=64 double-buffered.
// EPI 4 = csk scatter-add into trans_in[:,2::3] (skip u==U-1).
// EPI 5 = fusion: gate blend + all elementwise output splits.
template<int EPI>
__global__ __launch_bounds__(256) void mm64(
        const float* __restrict__ A1, const float* __restrict__ A2, int K1,
        const float* __restrict__ Bm, const float* __restrict__ bias,
        const float* __restrict__ ep1, const float* __restrict__ ep2,
        float* __restrict__ C, int N, int K,
        const float* __restrict__ sem_cls, unsigned short* __restrict__ deltaB,
        float* __restrict__ o_emo, float* __restrict__ o_lstra,
        float* __restrict__ o_ldelta)
{
    __shared__ __align__(16) unsigned short As[2][64][72];
    __shared__ __align__(16) unsigned short Bs[2][64][72];
    int tid = threadIdx.x;
    int wave = tid >> 6, lane = tid & 63;
    int l16 = lane & 15, g = lane >> 4;
    int wm = wave & 1, wn = wave >> 1;
    int row0 = blockIdx.y * 64, col0 = blockIdx.x * 64;

    int ar = tid >> 2, akq = (tid & 3) * 16;
    int bj0 = (tid & 31) * 2, kp = tid >> 5;
    float4 a0, a1, a2, a3;
    float2 b0[4], b1[4];

    auto loadT = [&](int k0) {
        int kk = k0 + akq;
        const float* src = (kk < K1) ? A1 + (size_t)(row0+ar)*K1 + kk
                                     : A2 + (size_t)(row0+ar)*(K-K1) + (kk-K1);
        a0 = *(const float4*)src;      a1 = *(const float4*)(src+4);
        a2 = *(const float4*)(src+8);  a3 = *(const float4*)(src+12);
        #pragma unroll
        for (int s = 0; s < 4; ++s) {
            int kb = 2*(kp + 8*s);
            const float* bp = Bm + (size_t)(k0 + kb)*N + col0 + bj0;
            b0[s] = *(const float2*)bp;
            b1[s] = *(const float2*)(bp + N);
        }
    };
    auto storeT = [&](int buf) {
        unsigned* da = (unsigned*)&As[buf][ar][akq];
        da[0]=pack2(a0.x,a0.y); da[1]=pack2(a0.z,a0.w);
        da[2]=pack2(a1.x,a1.y); da[3]=pack2(a1.z,a1.w);
        da[4]=pack2(a2.x,a2.y); da[5]=pack2(a2.z,a2.w);
        da[6]=pack2(a3.x,a3.y); da[7]=pack2(a3.z,a3.w);
        #pragma unroll
        for (int s = 0; s < 4; ++s) {
            int kb = 2*(kp + 8*s);
            *(unsigned*)&Bs[buf][bj0  ][kb] = pack2(b0[s].x, b1[s].x);
            *(unsigned*)&Bs[buf][bj0+1][kb] = pack2(b0[s].y, b1[s].y);
        }
    };

    f32x4 acc[2][2] = {};
    loadT(0); storeT(0);
    __syncthreads();
    int nt = K / 64;
    for (int t = 0; t < nt; ++t) {
        int cur = t & 1;
        if (t + 1 < nt) loadT((t+1)*64);
        #pragma unroll
        for (int kk = 0; kk < 2; ++kk) {
            bf16x8 af[2], bfr[2];
            #pragma unroll
            for (int mf = 0; mf < 2; ++mf) af[mf] = *(const bf16x8*)&As[cur][wm*32 + mf*16 + l16][kk*32 + g*8];
            #pragma unroll
            for (int nf = 0; nf < 2; ++nf) bfr[nf] = *(const bf16x8*)&Bs[cur][wn*32 + nf*16 + l16][kk*32 + g*8];
            #pragma unroll
            for (int mf = 0; mf < 2; ++mf)
                #pragma unroll
                for (int nf = 0; nf < 2; ++nf)
                    acc[mf][nf] = __builtin_amdgcn_mfma_f32_16x16x32_bf16(af[mf], bfr[nf], acc[mf][nf], 0, 0, 0);
        }
        if (t + 1 < nt) storeT(cur ^ 1);
        __syncthreads();
    }
    #pragma unroll
    for (int mf = 0; mf < 2; ++mf)
        #pragma unroll
        for (int nf = 0; nf < 2; ++nf) {
            int cc = col0 + wn*32 + nf*16 + l16;
            float bv = bias[cc];
            #pragma unroll
            for (int r = 0; r < 4; ++r) {
                int rr = row0 + wm*32 + mf*16 + g*4 + r;
                float v = acc[mf][nf][r] + bv;
                if (EPI == 4) {
                    int bq = rr / UU, uq = rr % UU;
                    if (uq < UU-1) {
                        float* dst = &C[((size_t)(bq*TT + 3*uq + 2))*DD + cc];
                        *dst += v;
                    }
                } else { // EPI == 5
                    float gg = 1.0f/(1.0f + __expf(-v));
                    float tv = ep1[(size_t)rr*N + cc];
                    float iv = ep2[(size_t)rr*N + cc];
                    float bl = gg*tv + (1.0f - gg)*iv;
                    C[(size_t)rr*N + cc] = bl;
                    int b = rr / TT, tt = rr % TT;
                    int m3 = tt % 3, u = tt / 3;
                    if (m3 == 0) {
                        float dl = bl - sem_cls[((size_t)(b*UU + u))*DD + cc];
                        deltaB[((size_t)(b*UU + u))*DD + cc] = f2b(dl);
                        if (u == UU-1) o_ldelta[b*DD + cc] = dl;
                    } else if (m3 == 1) {
                        if (u == UU-1) o_lstra[b*DD + cc] = bl;
                    } else {
                        o_emo[((size_t)(b*UU + u))*DD + cc] = bl;
                    }
                }
            }
        }
}

// ---------------------------------------------------------------------------
// Fused Q/K/V projection, BM=64 BN=64, BK=64 dbuf. Grid (48, 9).
__global__ __launch_bounds__(256) void mm_qkv(
        const float* __restrict__ x,
        const float* __restrict__ W0, const float* __restrict__ W1, const float* __restrict__ W2,
        const float* __restrict__ v0, const float* __restrict__ v1, const float* __restrict__ v2,
        float* __restrict__ C0, float* __restrict__ C1, float* __restrict__ C2)
{
    __shared__ __align__(16) unsigned short As[2][64][72];
    __shared__ __align__(16) unsigned short Bs[2][64][72];
    int which = blockIdx.x >> 4;
    int col0 = (blockIdx.x & 15) * 64;
    int row0 = blockIdx.y * 64;
    const float* W  = (which == 0) ? W0 : (which == 1) ? W1 : W2;
    const float* bb = (which == 0) ? v0 : (which == 1) ? v1 : v2;
    float*       C  = (which == 0) ? C0 : (which == 1) ? C1 : C2;
    int tid = threadIdx.x;
    int wave = tid >> 6, lane = tid & 63;
    int l16 = lane & 15, g = lane >> 4;
    int wm = wave & 1, wn = wave >> 1;

    int ar = tid >> 2, akq = (tid & 3) * 16;
    int bj0 = (tid & 31) * 2, kp = tid >> 5;
    float4 a0, a1, a2, a3;
    float2 b0[4], b1[4];

    auto loadT = [&](int k0) {
        const float* src = x + (size_t)(row0+ar)*DD + k0 + akq;
        a0 = *(const float4*)src;      a1 = *(const float4*)(src+4);
        a2 = *(const float4*)(src+8);  a3 = *(const float4*)(src+12);
        #pragma unroll
        for (int s = 0; s < 4; ++s) {
            int kb = 2*(kp + 8*s);
            const float* bp = W + (size_t)(k0 + kb)*DD + col0 + bj0;
            b0[s] = *(const float2*)bp;
            b1[s] = *(const float2*)(bp + DD);
        }
    };
    auto storeT = [&](int buf) {
        unsigned* da = (unsigned*)&As[buf][ar][akq];
        da[0]=pack2(a0.x,a0.y); da[1]=pack2(a0.z,a0.w);
        da[2]=pack2(a1.x,a1.y); da[3]=pack2(a1.z,a1.w);
        da[4]=pack2(a2.x,a2.y); da[5]=pack2(a2.z,a2.w);
        da[6]=pack2(a3.x,a3.y); da[7]=pack2(a3.z,a3.w);
        #pragma unroll
        for (int s = 0; s < 4; ++s) {
            int kb = 2*(kp + 8*s);
            *(unsigned*)&Bs[buf][bj0  ][kb] = pack2(b0[s].x, b1[s].x);
            *(unsigned*)&Bs[buf][bj0+1][kb] = pack2(b0[s].y, b1[s].y);
        }
    };

    f32x4 acc[2][2] = {};
    loadT(0); storeT(0);
    __syncthreads();
    for (int t = 0; t < 16; ++t) {
        int cur = t & 1;
        if (t < 15) loadT((t+1)*64);
        #pragma unroll
        for (int kk = 0; kk < 2; ++kk) {
            bf16x8 af[2], bfr[2];
            #pragma unroll
            for (int mf = 0; mf < 2; ++mf) af[mf] = *(const bf16x8*)&As[cur][wm*32 + mf*16 + l16][kk*32 + g*8];
            #pragma unroll
            for (int nf = 0; nf < 2; ++nf) bfr[nf] = *(const bf16x8*)&Bs[cur][wn*32 + nf*16 + l16][kk*32 + g*8];
            #pragma unroll
            for (int mf = 0; mf < 2; ++mf)
                #pragma unroll
                for (int nf = 0; nf < 2; ++nf)
                    acc[mf][nf] = __builtin_amdgcn_mfma_f32_16x16x32_bf16(af[mf], bfr[nf], acc[mf][nf], 0, 0, 0);
        }
        if (t < 15) storeT(cur ^ 1);
        __syncthreads();
    }
    #pragma unroll
    for (int mf = 0; mf < 2; ++mf)
        #pragma unroll
        for (int nf = 0; nf < 2; ++nf) {
            int cc = col0 + wn*32 + nf*16 + l16;
            float bv = bb[cc];
            #pragma unroll
            for (int r = 0; r < 4; ++r) {
                int rr = row0 + wm*32 + mf*16 + g*4 + r;
                C[(size_t)rr*DD + cc] = acc[mf][nf][r] + bv;
            }
        }
}

// ---------------------------------------------------------------------------
// bow GEMM v8: deltaB(bf16)[192,1024] @ bowW[1024,54945] -> o_bow.
// BARRIER-FREE k-loop: each wave owns 48 rows (3 frags) staged in its own
// PRIVATE LDS region (lgkmcnt only, no __syncthreads -> vmcnt B-prefetch
// queue never drains). Block = 192 rows x 16 cols; grid 3435 (13.4 blk/CU).
// A-chunk global loads issued at superstep START so the vmcnt wait before
// WRITEA only covers loads already due; in-superstep B prefetches survive.
__global__ __launch_bounds__(256) void mm_bow(
        const unsigned short* __restrict__ Ab, const float* __restrict__ Bm,
        float* __restrict__ C)
{
    __shared__ __align__(16) unsigned short A_lds[4][48][136];   // 52.2 KB
    const int N = NVOCAB;
    int tid = threadIdx.x;
    int lane = tid & 63, w = tid >> 6;
    int l16 = lane & 15, g = lane >> 4;
    int col = blockIdx.x * 16 + l16;
    int colc = (col < N) ? col : (N - 1);
    const float* bbase = Bm + (size_t)(g * 8) * N + colc;

    // per-wave A staging: 48 rows x 128 k per chunk = 12 int4 per lane
    int4 ar0, ar1, ar2, ar3, ar4, ar5, ar6, ar7, ar8, ar9, ar10, ar11;
#define AIDX(i) int rr##i = ((i)*64 + lane) >> 4, ck##i = (((i)*64 + lane) & 15) * 8
    AIDX(0); AIDX(1); AIDX(2); AIDX(3); AIDX(4); AIDX(5);
    AIDX(6); AIDX(7); AIDX(8); AIDX(9); AIDX(10); AIDX(11);
#undef AIDX
    const unsigned short* abase = Ab + (size_t)(w * 48) * DD;
#define LOADA(s) { const unsigned short* ab = abase + (s) * 128;               \
        ar0  = *(const int4*)(ab + (size_t)rr0*DD  + ck0);                     \
        ar1  = *(const int4*)(ab + (size_t)rr1*DD  + ck1);                     \
        ar2  = *(const int4*)(ab + (size_t)rr2*DD  + ck2);                     \
        ar3  = *(const int4*)(ab + (size_t)rr3*DD  + ck3);                     \
        ar4  = *(const int4*)(ab + (size_t)rr4*DD  + ck4);                     \
        ar5  = *(const int4*)(ab + (size_t)rr5*DD  + ck5);                     \
        ar6  = *(const int4*)(ab + (size_t)rr6*DD  + ck6);                     \
        ar7  = *(const int4*)(ab + (size_t)rr7*DD  + ck7);                     \
        ar8  = *(const int4*)(ab + (size_t)rr8*DD  + ck8);                     \
        ar9  = *(const int4*)(ab + (size_t)rr9*DD  + ck9);                     \
        ar10 = *(const int4*)(ab + (size_t)rr10*DD + ck10);                    \
        ar11 = *(const int4*)(ab + (size_t)rr11*DD + ck11);                    \
    }
#define WRITEA() {                                                             \
        *(int4*)&A_lds[w][rr0][ck0]   = ar0;  *(int4*)&A_lds[w][rr1][ck1]   = ar1; \
        *(int4*)&A_lds[w][rr2][ck2]   = ar2;  *(int4*)&A_lds[w][rr3][ck3]   = ar3; \
        *(int4*)&A_lds[w][rr4][ck4]   = ar4;  *(int4*)&A_lds[w][rr5][ck5]   = ar5; \
        *(int4*)&A_lds[w][rr6][ck6]   = ar6;  *(int4*)&A_lds[w][rr7][ck7]   = ar7; \
        *(int4*)&A_lds[w][rr8][ck8]   = ar8;  *(int4*)&A_lds[w][rr9][ck9]   = ar9; \
        *(int4*)&A_lds[w][rr10][ck10] = ar10; *(int4*)&A_lds[w][rr11][ck11] = ar11; \
    }

    f32x4 acc[3] = {};
    float bs[4][8];

#define LOADB(dst, t_) { const float* bp = bbase + (size_t)(t_) * 32 * N;      \
        _Pragma("unroll") for (int j = 0; j < 8; ++j) dst[j] = bp[(size_t)j * N]; }
#define PACKB(fr, sv) { _Pragma("unroll") for (int j = 0; j < 8; ++j)          \
        ((unsigned short*)&fr)[j] = f2b(sv[j]); }

    LOADA(0); WRITEA();
    #pragma unroll
    for (int p = 0; p < 4; ++p) LOADB(bs[p], p);

    for (int s = 0; s < 8; ++s) {
        if (s < 7) LOADA(s + 1);            // issued before this superstep's B
        #pragma unroll
        for (int p = 0; p < 4; ++p) {
            int P = s*4 + p;
            bf16x8 fr;
            PACKB(fr, bs[p]);
            if (P + 4 < 32) LOADB(bs[p], P + 4);
            #pragma unroll
            for (int mf = 0; mf < 3; ++mf) {
                bf16x8 af = *(const bf16x8*)&A_lds[w][mf*16 + l16][p*32 + g*8];
                acc[mf] = __builtin_amdgcn_mfma_f32_16x16x32_bf16(af, fr, acc[mf], 0, 0, 0);
            }
        }
        if (s < 7) WRITEA();                // lgkmcnt-only; no barrier needed
    }
#undef LOADA
#undef WRITEA
#undef LOADB
#undef PACKB
    if (col < N) {
        #pragma unroll
        for (int mf = 0; mf < 3; ++mf)
            #pragma unroll
            for (int r = 0; r < 4; ++r)
                C[(size_t)(w*48 + mf*16 + g*4 + r) * N + col] = acc[mf][r];
    }
}

// ---------------------------------------------------------------------------
// Fully fused attention per (b,h,half): edge prefix in-block, prep + scores +
// softmax + PV. 256 blocks, 512 thr. Q rows batch-prefetched.
__global__ __launch_bounds__(512) void k_attn(const float* __restrict__ Qb,
        const float* __restrict__ Kg, const float* __restrict__ Vg,
        const int* __restrict__ et, const float* __restrict__ rel,
        const int* __restrict__ mask, float* __restrict__ out)
{
    int bid = blockIdx.x;
    int is = bid & 1;
    int h  = (bid >> 1) & (HH-1);
    int b  = bid >> 5;
    int lo = is * (TT/2);
    __shared__ float K_sh[DH][TT+1];
    __shared__ float V_sh[TT][DH];
    __shared__ uint2 cnt_sh[TT/2][TT];
    __shared__ __align__(16) unsigned char un_raw[6400];
    float (*rel_sh)[DH] = (float(*)[DH])un_raw;
    float (*a_row)[DH]  = (float(*)[DH])(un_raw + 2048);
    float (*p_row)[TT]  = (float(*)[TT])(un_raw + 4096);
    unsigned char* e_sh = un_raw;
    int tid = threadIdx.x;
    int lane = tid & 63, w = tid >> 6;

    for (int idx = tid; idx < TT*16; idx += 512) {
        int r = idx >> 4, q4 = (idx & 15) * 4;
        size_t goff = ((size_t)(b*TT + r))*DD + h*DH + q4;
        float4 kv = *(const float4*)&Kg[goff];
        K_sh[q4  ][r] = kv.x; K_sh[q4+1][r] = kv.y;
        K_sh[q4+2][r] = kv.z; K_sh[q4+3][r] = kv.w;
        float4 vv = *(const float4*)&Vg[goff];
        *(float4*)&V_sh[r][q4] = vv;
    }
    for (int idx = tid; idx < (TT*TT)/4; idx += 512) {
        int4 v = ((const int4*)(et + (size_t)b*TT*TT))[idx];
        unsigned pk = (unsigned)v.x | ((unsigned)v.y << 8) | ((unsigned)v.z << 16) | ((unsigned)v.w << 24);
        *(unsigned*)&e_sh[idx*4] = pk;
    }
    __syncthreads();
    if (tid < TT) {
        unsigned lo32 = 0, hi32 = 0;
        int iend = lo + TT/2;
        for (int i = 0; i < iend; ++i) {
            int r = e_sh[i*TT + tid];
            if (r < 4) lo32 += 1u << (8*r); else hi32 += 1u << (8*(r-4));
            if (i >= lo) cnt_sh[i - lo][tid] = make_uint2(lo32, hi32);
        }
    }
    __syncthreads();
    if (tid < 128) {
        int r = tid >> 4, q4 = (tid & 15) * 4;
        *(float4*)&rel_sh[r][q4] = *(const float4*)&rel[r*DD + h*DH + q4];
    }
    __syncthreads();

    auto processRow = [&](float q, int ii) {
        int i = lo + ii;
        size_t rowoff = (size_t)(b*TT + i);
        float crd[8]; dec8(cnt_sh[ii][i], crd);
        float a = q;
        #pragma unroll
        for (int r = 0; r < 8; ++r) a += crd[r]*rel_sh[r][lane];
        a_row[w][lane] = a;
        float arr[8];
        #pragma unroll
        for (int r = 0; r < 8; ++r) {
            float pr = a * rel_sh[r][lane];
            #pragma unroll
            for (int off = 32; off; off >>= 1) pr += __shfl_xor(pr, off);
            arr[r] = pr;
        }
        float s1;
        {
            int t = lane;
            float s = 0.0f;
            #pragma unroll
            for (int d0 = 0; d0 < DH; d0 += 4) {
                float4 av = *(const float4*)&a_row[w][d0];
                s += av.x*K_sh[d0][t] + av.y*K_sh[d0+1][t]
                   + av.z*K_sh[d0+2][t] + av.w*K_sh[d0+3][t];
            }
            float cr2[8]; dec8(cnt_sh[ii][t], cr2);
            float s2v = cr2[0]*arr[0] + cr2[1]*arr[1] + cr2[2]*arr[2] + cr2[3]*arr[3]
                      + cr2[4]*arr[4] + cr2[5]*arr[5] + cr2[6]*arr[6] + cr2[7]*arr[7];
            int m = mask[rowoff*TT + t];
            s1 = (m == 0) ? -1e9f : (s + s2v)*0.125f;
        }
        float s2 = -1e30f;
        if (lane < TT - DH) {
            int t = DH + lane;
            float s = 0.0f;
            #pragma unroll
            for (int d0 = 0; d0 < DH; d0 += 4) {
                float4 av = *(const float4*)&a_row[w][d0];
                s += av.x*K_sh[d0][t] + av.y*K_sh[d0+1][t]
                   + av.z*K_sh[d0+2][t] + av.w*K_sh[d0+3][t];
            }
            float cr2[8]; dec8(cnt_sh[ii][t], cr2);
            float s2v = cr2[0]*arr[0] + cr2[1]*arr[1] + cr2[2]*arr[2] + cr2[3]*arr[3]
                      + cr2[4]*arr[4] + cr2[5]*arr[5] + cr2[6]*arr[6] + cr2[7]*arr[7];
            int m = mask[rowoff*TT + t];
            s2 = (m == 0) ? -1e9f : (s + s2v)*0.125f;
        }
        float mx = fmaxf(s1, s2);
        #pragma unroll
        for (int off = 32; off; off >>= 1) mx = fmaxf(mx, __shfl_xor(mx, off));
        float e1 = __expf(s1 - mx);
        float e2 = (lane < TT - DH) ? __expf(s2 - mx) : 0.0f;
        float sm = e1 + e2;
        #pragma unroll
        for (int off = 32; off; off >>= 1) sm += __shfl_xor(sm, off);
        float inv = 1.0f / sm;
        p_row[w][lane] = e1 * inv;
        if (lane < TT - DH) p_row[w][DH + lane] = e2 * inv;
        float o = 0.0f;
        #pragma unroll 8
        for (int t = 0; t < TT; ++t) o += p_row[w][t] * V_sh[t][lane];
        out[rowoff*DD + h*DH + lane] = o;
    };

    float qv0, qv1, qv2, qv3, qv4 = 0.0f;
    {
        size_t base = ((size_t)(b*TT + lo + w))*DD + h*DH + lane;
        qv0 = Qb[base];
        qv1 = Qb[base + (size_t)8*DD];
        qv2 = Qb[base + (size_t)16*DD];
        qv3 = Qb[base + (size_t)24*DD];
        if (w < 4) qv4 = Qb[base + (size_t)32*DD];
    }
    processRow(qv0, w);
    processRow(qv1, w + 8);
    processRow(qv2, w + 16);
    processRow(qv3, w + 24);
    if (w < 4) processRow(qv4, w + 32);
}

// ---------------------------------------------------------------------------
// strategy (8) and emotion (6) logits
__global__ __launch_bounds__(256) void k_logits(const float* __restrict__ outs,
        const float* __restrict__ strW, const float* __restrict__ strB,
        const float* __restrict__ emoW, const float* __restrict__ emoB,
        float* __restrict__ o_str, float* __restrict__ o_emo_log)
{
    __shared__ float part[14][16];
    int bid = blockIdx.x; int b = bid / UU, u = bid % UU;
    const float* st = outs + ((size_t)(b*TT + 3*u + 1))*DD;
    const float* em = st + DD;
    int t = threadIdx.x;
    if (t < 224) {
        int o = t >> 4, c = t & 15;
        float s = 0.0f;
        if (o < 8) {
            for (int d = c*64; d < c*64 + 64; ++d) s += st[d]*strW[d*8 + o];
        } else {
            int j = o - 8;
            for (int d = c*64; d < c*64 + 64; ++d) s += em[d]*emoW[d*6 + j];
        }
        part[o][c] = s;
    }
    __syncthreads();
    if (t < 14) {
        float s = 0.0f;
        #pragma unroll
        for (int c2 = 0; c2 < 16; ++c2) s += part[t][c2];
        if (t < 8) o_str[(b*UU + u)*8 + t] = s + strB[t];
        else       o_emo_log[(b*UU + u)*6 + (t-8)] = s + emoB[t-8];
    }
}

// ---------------------------------------------------------------------------
extern "C" void kernel_launch(void* const* d_in, const int* in_sizes, int n_in,
                              void* d_out, int out_size, void* d_ws, size_t ws_size,
                              hipStream_t stream)
{
    const float* hidden  = (const float*)d_in[0];
    const float* emo_csk = (const float*)d_in[1];
    const float* Wq  = (const float*)d_in[2];
    const float* bq  = (const float*)d_in[3];
    const float* Wk  = (const float*)d_in[4];
    const float* bk  = (const float*)d_in[5];
    const float* Wv  = (const float*)d_in[6];
    const float* bv  = (const float*)d_in[7];
    const float* rel = (const float*)d_in[8];
    const float* fusW = (const float*)d_in[9];
    const float* fusB = (const float*)d_in[10];
    const float* bng = (const float*)d_in[11];
    const float* bnb = (const float*)d_in[12];
    const float* bnm = (const float*)d_in[13];
    const float* bnv = (const float*)d_in[14];
    const float* cskW = (const float*)d_in[15];
    const float* cskB = (const float*)d_in[16];
    const float* emoW = (const float*)d_in[17];
    const float* emoB = (const float*)d_in[18];
    const float* strW = (const float*)d_in[19];
    const float* strB = (const float*)d_in[20];
    const float* bowW = (const float*)d_in[21];
    const int* clsIdx = (const int*)d_in[22];
    const int* tGraph = (const int*)d_in[23];
    const int* iGraph = (const int*)d_in[24];
    const int* tEdge  = (const int*)d_in[25];
    const int* iEdge  = (const int*)d_in[26];

    float* out = (float*)d_out;
    float* o_last_stra  = out;             // B*D          = 8192
    float* o_emo_trans  = out + 8192;      // B*U*D        = 196608
    float* o_last_delta = out + 204800;    // B*D          = 8192
    float* o_sem_cls    = out + 212992;    // B*U*D        = 196608
    float* o_str_log    = out + 409600;    // B*U*8        = 1536
    float* o_emo_log    = out + 411136;    // B*U*6        = 1152
    float* o_bow        = out + 412288;    // B*U*VOCAB

    float* ws = (float*)d_ws;
    const int SZ_BTD = BB*TT*DD;   // 589824
    const int SZ_BUD = BB*UU*DD;   // 196608
    float* trans_in  = ws;
    float* Qb        = trans_in + SZ_BTD;
    float* Kb        = Qb + SZ_BTD;
    float* Vb        = Kb + SZ_BTD;
    float* trans_out = Vb + SZ_BTD;
    float* inter_out = trans_out + SZ_BTD;
    float* outsB     = inter_out + SZ_BTD;
    float* csk_norm  = outsB + SZ_BTD;
    unsigned short* deltaB = (unsigned short*)(csk_norm + SZ_BUD);

    // 1. gather cls + batchnorm (merged, grid-split)
    k_gather_bn<<<dim3(BB*UU + (BB*UU*CSKN+255)/256), dim3(256), 0, stream>>>(
            hidden, clsIdx, o_sem_cls, trans_in, emo_csk, bng, bnb, bnm, bnv, csk_norm);
    // 2. csk_proj GEMM fused with scatter-add into trans_in[:,2::3]
    mm64<4><<<dim3(16, 3), dim3(256), 0, stream>>>(csk_norm, nullptr, CSKN, cskW, cskB,
            nullptr, nullptr, trans_in, DD, CSKN, nullptr, nullptr, nullptr, nullptr, nullptr);

    auto attention = [&](const float* x, const int* graph, const int* edge, float* ctx_out) {
        mm_qkv<<<dim3(48, (BB*TT)/64), dim3(256), 0, stream>>>(x, Wq, Wk, Wv, bq, bk, bv, Qb, Kb, Vb);
        k_attn<<<dim3(BB*HH*2), dim3(512), 0, stream>>>(Qb, Kb, Vb, edge, rel, graph, ctx_out);
    };
    attention(trans_in, tGraph, tEdge, trans_out);
    attention(trans_out, iGraph, iEdge, inter_out);

    // fusion gate + blend + ALL elementwise output splits (EPI=5)
    mm64<5><<<dim3(16, (BB*TT)/64), dim3(256), 0, stream>>>(trans_out, inter_out, DD, fusW, fusB,
            trans_out, inter_out, outsB, DD, 2*DD,
            o_sem_cls, deltaB, o_emo_trans, o_last_stra, o_last_delta);

    // strategy/emotion logits
    k_logits<<<dim3(BB*UU), dim3(256), 0, stream>>>(outsB, strW, strB, emoW, emoB,
            o_str_log, o_emo_log);

    // bow_logits = delta @ bow_W (barrier-free k-loop, per-wave private A LDS)
    mm_bow<<<dim3((NVOCAB+15)/16), dim3(256), 0, stream>>>(deltaB, bowW, o_bow);
}

// Round 16
// 263.860 us; speedup vs baseline: 1.4208x; 1.4208x over previous
//
#include <hip/hip_runtime.h>
#include <math.h>

// Problem constants
#define BB 8
#define LL 512
#define UU 24
#define DD 1024
#define HH 16
#define DH 64
#define TT 72
#define CSKN 1024
#define NVOCAB 54945

typedef __attribute__((ext_vector_type(8))) short bf16x8;
typedef __attribute__((ext_vector_type(4))) float f32x4;

__device__ inline unsigned short f2b(float x) {
    unsigned u = __float_as_uint(x);
    unsigned r = u + 0x7FFFu + ((u >> 16) & 1u);
    return (unsigned short)(r >> 16);
}
__device__ inline unsigned pack2(float lo, float hi) {
    return (unsigned)f2b(lo) | ((unsigned)f2b(hi) << 16);
}
__device__ inline void dec8(uint2 c, float* cr) {
    cr[0] = (float)( c.x        & 0xff); cr[1] = (float)((c.x >>  8) & 0xff);
    cr[2] = (float)((c.x >> 16) & 0xff); cr[3] = (float)((c.x >> 24) & 0xff);
    cr[4] = (float)( c.y        & 0xff); cr[5] = (float)((c.y >>  8) & 0xff);
    cr[6] = (float)((c.y >> 16) & 0xff); cr[7] = (float)((c.y >> 24) & 0xff);
}

// ---------------------------------------------------------------------------
// Merged: gather cls (blocks 0..191) + batchnorm (blocks 192..959)
__global__ __launch_bounds__(256) void k_gather_bn(const float* __restrict__ hidden,
        const int* __restrict__ idx, float* __restrict__ sem_cls, float* __restrict__ trans_in,
        const float* __restrict__ x, const float* __restrict__ g,
        const float* __restrict__ be, const float* __restrict__ mu,
        const float* __restrict__ var, float* __restrict__ y)
{
    int bid = blockIdx.x;
    if (bid < BB*UU) {
        int b = bid / UU, u = bid % UU;
        int row = idx[b*UU + u];
        const float* src = hidden + ((size_t)(b*LL + row))*DD;
        float* d0 = trans_in + ((size_t)(b*TT + 3*u))*DD;
        float* sc = sem_cls + ((size_t)(b*UU + u))*DD;
        for (int d = threadIdx.x; d < DD; d += 256) {
            float v = src[d];
            sc[d] = v;
            d0[d] = v; d0[DD + d] = v; d0[2*DD + d] = v;
        }
    } else {
        int i = (bid - BB*UU)*256 + threadIdx.x;
        int n = BB*UU*CSKN;
        if (i < n) {
            int c = i % CSKN;
            y[i] = (x[i] - mu[c]) * (1.0f/sqrtf(var[c] + 1e-5f)) * g[c] + be[c];
        }
    }
}

// ---------------------------------------------------------------------------
// MFMA bf16 GEMM, 64x64 tile, BK=64 double-buffered.
// EPI 4 = csk scatter-add into trans_in[:,2::3] (skip u==U-1).
// EPI 5 = fusion: gate blend + all elementwise output splits.
template<int EPI>
__global__ __launch_bounds__(256) void mm64(
        const float* __restrict__ A1, const float* __restrict__ A2, int K1,
        const float* __restrict__ Bm, const float* __restrict__ bias,
        const float* __restrict__ ep1, const float* __restrict__ ep2,
        float* __restrict__ C, int N, int K,
        const float* __restrict__ sem_cls, unsigned short* __restrict__ deltaB,
        float* __restrict__ o_emo, float* __restrict__ o_lstra,
        float* __restrict__ o_ldelta)
{
    __shared__ __align__(16) unsigned short As[2][64][72];
    __shared__ __align__(16) unsigned short Bs[2][64][72];
    int tid = threadIdx.x;
    int wave = tid >> 6, lane = tid & 63;
    int l16 = lane & 15, g = lane >> 4;
    int wm = wave & 1, wn = wave >> 1;
    int row0 = blockIdx.y * 64, col0 = blockIdx.x * 64;

    int ar = tid >> 2, akq = (tid & 3) * 16;
    int bj0 = (tid & 31) * 2, kp = tid >> 5;
    float4 a0, a1, a2, a3;
    float2 b0[4], b1[4];

    auto loadT = [&](int k0) {
        int kk = k0 + akq;
        const float* src = (kk < K1) ? A1 + (size_t)(row0+ar)*K1 + kk
                                     : A2 + (size_t)(row0+ar)*(K-K1) + (kk-K1);
        a0 = *(const float4*)src;      a1 = *(const float4*)(src+4);
        a2 = *(const float4*)(src+8);  a3 = *(const float4*)(src+12);
        #pragma unroll
        for (int s = 0; s < 4; ++s) {
            int kb = 2*(kp + 8*s);
            const float* bp = Bm + (size_t)(k0 + kb)*N + col0 + bj0;
            b0[s] = *(const float2*)bp;
            b1[s] = *(const float2*)(bp + N);
        }
    };
    auto storeT = [&](int buf) {
        unsigned* da = (unsigned*)&As[buf][ar][akq];
        da[0]=pack2(a0.x,a0.y); da[1]=pack2(a0.z,a0.w);
        da[2]=pack2(a1.x,a1.y); da[3]=pack2(a1.z,a1.w);
        da[4]=pack2(a2.x,a2.y); da[5]=pack2(a2.z,a2.w);
        da[6]=pack2(a3.x,a3.y); da[7]=pack2(a3.z,a3.w);
        #pragma unroll
        for (int s = 0; s < 4; ++s) {
            int kb = 2*(kp + 8*s);
            *(unsigned*)&Bs[buf][bj0  ][kb] = pack2(b0[s].x, b1[s].x);
            *(unsigned*)&Bs[buf][bj0+1][kb] = pack2(b0[s].y, b1[s].y);
        }
    };

    f32x4 acc[2][2] = {};
    loadT(0); storeT(0);
    __syncthreads();
    int nt = K / 64;
    for (int t = 0; t < nt; ++t) {
        int cur = t & 1;
        if (t + 1 < nt) loadT((t+1)*64);
        #pragma unroll
        for (int kk = 0; kk < 2; ++kk) {
            bf16x8 af[2], bfr[2];
            #pragma unroll
            for (int mf = 0; mf < 2; ++mf) af[mf] = *(const bf16x8*)&As[cur][wm*32 + mf*16 + l16][kk*32 + g*8];
            #pragma unroll
            for (int nf = 0; nf < 2; ++nf) bfr[nf] = *(const bf16x8*)&Bs[cur][wn*32 + nf*16 + l16][kk*32 + g*8];
            #pragma unroll
            for (int mf = 0; mf < 2; ++mf)
                #pragma unroll
                for (int nf = 0; nf < 2; ++nf)
                    acc[mf][nf] = __builtin_amdgcn_mfma_f32_16x16x32_bf16(af[mf], bfr[nf], acc[mf][nf], 0, 0, 0);
        }
        if (t + 1 < nt) storeT(cur ^ 1);
        __syncthreads();
    }
    #pragma unroll
    for (int mf = 0; mf < 2; ++mf)
        #pragma unroll
        for (int nf = 0; nf < 2; ++nf) {
            int cc = col0 + wn*32 + nf*16 + l16;
            float bv = bias[cc];
            #pragma unroll
            for (int r = 0; r < 4; ++r) {
                int rr = row0 + wm*32 + mf*16 + g*4 + r;
                float v = acc[mf][nf][r] + bv;
                if (EPI == 4) {
                    int bq = rr / UU, uq = rr % UU;
                    if (uq < UU-1) {
                        float* dst = &C[((size_t)(bq*TT + 3*uq + 2))*DD + cc];
                        *dst += v;
                    }
                } else { // EPI == 5
                    float gg = 1.0f/(1.0f + __expf(-v));
                    float tv = ep1[(size_t)rr*N + cc];
                    float iv = ep2[(size_t)rr*N + cc];
                    float bl = gg*tv + (1.0f - gg)*iv;
                    C[(size_t)rr*N + cc] = bl;
                    int b = rr / TT, tt = rr % TT;
                    int m3 = tt % 3, u = tt / 3;
                    if (m3 == 0) {
                        float dl = bl - sem_cls[((size_t)(b*UU + u))*DD + cc];
                        deltaB[((size_t)(b*UU + u))*DD + cc] = f2b(dl);
                        if (u == UU-1) o_ldelta[b*DD + cc] = dl;
                    } else if (m3 == 1) {
                        if (u == UU-1) o_lstra[b*DD + cc] = bl;
                    } else {
                        o_emo[((size_t)(b*UU + u))*DD + cc] = bl;
                    }
                }
            }
        }
}

// ---------------------------------------------------------------------------
// Fused Q/K/V projection, BM=64 BN=64, BK=64 dbuf. Grid (48, 9).
__global__ __launch_bounds__(256) void mm_qkv(
        const float* __restrict__ x,
        const float* __restrict__ W0, const float* __restrict__ W1, const float* __restrict__ W2,
        const float* __restrict__ v0, const float* __restrict__ v1, const float* __restrict__ v2,
        float* __restrict__ C0, float* __restrict__ C1, float* __restrict__ C2)
{
    __shared__ __align__(16) unsigned short As[2][64][72];
    __shared__ __align__(16) unsigned short Bs[2][64][72];
    int which = blockIdx.x >> 4;
    int col0 = (blockIdx.x & 15) * 64;
    int row0 = blockIdx.y * 64;
    const float* W  = (which == 0) ? W0 : (which == 1) ? W1 : W2;
    const float* bb = (which == 0) ? v0 : (which == 1) ? v1 : v2;
    float*       C  = (which == 0) ? C0 : (which == 1) ? C1 : C2;
    int tid = threadIdx.x;
    int wave = tid >> 6, lane = tid & 63;
    int l16 = lane & 15, g = lane >> 4;
    int wm = wave & 1, wn = wave >> 1;

    int ar = tid >> 2, akq = (tid & 3) * 16;
    int bj0 = (tid & 31) * 2, kp = tid >> 5;
    float4 a0, a1, a2, a3;
    float2 b0[4], b1[4];

    auto loadT = [&](int k0) {
        const float* src = x + (size_t)(row0+ar)*DD + k0 + akq;
        a0 = *(const float4*)src;      a1 = *(const float4*)(src+4);
        a2 = *(const float4*)(src+8);  a3 = *(const float4*)(src+12);
        #pragma unroll
        for (int s = 0; s < 4; ++s) {
            int kb = 2*(kp + 8*s);
            const float* bp = W + (size_t)(k0 + kb)*DD + col0 + bj0;
            b0[s] = *(const float2*)bp;
            b1[s] = *(const float2*)(bp + DD);
        }
    };
    auto storeT = [&](int buf) {
        unsigned* da = (unsigned*)&As[buf][ar][akq];
        da[0]=pack2(a0.x,a0.y); da[1]=pack2(a0.z,a0.w);
        da[2]=pack2(a1.x,a1.y); da[3]=pack2(a1.z,a1.w);
        da[4]=pack2(a2.x,a2.y); da[5]=pack2(a2.z,a2.w);
        da[6]=pack2(a3.x,a3.y); da[7]=pack2(a3.z,a3.w);
        #pragma unroll
        for (int s = 0; s < 4; ++s) {
            int kb = 2*(kp + 8*s);
            *(unsigned*)&Bs[buf][bj0  ][kb] = pack2(b0[s].x, b1[s].x);
            *(unsigned*)&Bs[buf][bj0+1][kb] = pack2(b0[s].y, b1[s].y);
        }
    };

    f32x4 acc[2][2] = {};
    loadT(0); storeT(0);
    __syncthreads();
    for (int t = 0; t < 16; ++t) {
        int cur = t & 1;
        if (t < 15) loadT((t+1)*64);
        #pragma unroll
        for (int kk = 0; kk < 2; ++kk) {
            bf16x8 af[2], bfr[2];
            #pragma unroll
            for (int mf = 0; mf < 2; ++mf) af[mf] = *(const bf16x8*)&As[cur][wm*32 + mf*16 + l16][kk*32 + g*8];
            #pragma unroll
            for (int nf = 0; nf < 2; ++nf) bfr[nf] = *(const bf16x8*)&Bs[cur][wn*32 + nf*16 + l16][kk*32 + g*8];
            #pragma unroll
            for (int mf = 0; mf < 2; ++mf)
                #pragma unroll
                for (int nf = 0; nf < 2; ++nf)
                    acc[mf][nf] = __builtin_amdgcn_mfma_f32_16x16x32_bf16(af[mf], bfr[nf], acc[mf][nf], 0, 0, 0);
        }
        if (t < 15) storeT(cur ^ 1);
        __syncthreads();
    }
    #pragma unroll
    for (int mf = 0; mf < 2; ++mf)
        #pragma unroll
        for (int nf = 0; nf < 2; ++nf) {
            int cc = col0 + wn*32 + nf*16 + l16;
            float bv = bb[cc];
            #pragma unroll
            for (int r = 0; r < 4; ++r) {
                int rr = row0 + wm*32 + mf*16 + g*4 + r;
                C[(size_t)rr*DD + cc] = acc[mf][nf][r] + bv;
            }
        }
}

// ---------------------------------------------------------------------------
// bow GEMM (R11, session-best measured): deltaB(bf16)[192,1024] @ bowW.
// Barriers every 4 k-steps; B direct from global with 4-deep prefetch.
__global__ __launch_bounds__(256, 1) void mm_bow(
        const unsigned short* __restrict__ Ab, const float* __restrict__ Bm,
        float* __restrict__ C)
{
    __shared__ __align__(16) unsigned short A_lds[192][136];   // 52.2 KB
    const int N = NVOCAB;
    int tid = threadIdx.x;
    int lane = tid & 63, wave = tid >> 6;
    int l16 = lane & 15, g = lane >> 4;
    int col = blockIdx.x * 64 + wave * 16 + l16;
    int colc = (col < N) ? col : (N - 1);
    const float* bbase = Bm + (size_t)(g * 8) * N + colc;

    int4 areg0, areg1, areg2, areg3, areg4, areg5, areg6, areg7, areg8, areg9, areg10, areg11;
#define AIDX(i) int r##i = ((i)*256 + tid) >> 4, c##i = (((i)*256 + tid) & 15) * 8
    AIDX(0); AIDX(1); AIDX(2); AIDX(3); AIDX(4); AIDX(5);
    AIDX(6); AIDX(7); AIDX(8); AIDX(9); AIDX(10); AIDX(11);
#undef AIDX
#define LOADA(s) {                                                             \
        const unsigned short* ab = Ab + (s)*128;                               \
        areg0  = *(const int4*)(ab + (size_t)r0*DD  + c0);                     \
        areg1  = *(const int4*)(ab + (size_t)r1*DD  + c1);                     \
        areg2  = *(const int4*)(ab + (size_t)r2*DD  + c2);                     \
        areg3  = *(const int4*)(ab + (size_t)r3*DD  + c3);                     \
        areg4  = *(const int4*)(ab + (size_t)r4*DD  + c4);                     \
        areg5  = *(const int4*)(ab + (size_t)r5*DD  + c5);                     \
        areg6  = *(const int4*)(ab + (size_t)r6*DD  + c6);                     \
        areg7  = *(const int4*)(ab + (size_t)r7*DD  + c7);                     \
        areg8  = *(const int4*)(ab + (size_t)r8*DD  + c8);                     \
        areg9  = *(const int4*)(ab + (size_t)r9*DD  + c9);                     \
        areg10 = *(const int4*)(ab + (size_t)r10*DD + c10);                    \
        areg11 = *(const int4*)(ab + (size_t)r11*DD + c11);                    \
    }
#define WRITEA() {                                                             \
        *(int4*)&A_lds[r0][c0]   = areg0;  *(int4*)&A_lds[r1][c1]   = areg1;   \
        *(int4*)&A_lds[r2][c2]   = areg2;  *(int4*)&A_lds[r3][c3]   = areg3;   \
        *(int4*)&A_lds[r4][c4]   = areg4;  *(int4*)&A_lds[r5][c5]   = areg5;   \
        *(int4*)&A_lds[r6][c6]   = areg6;  *(int4*)&A_lds[r7][c7]   = areg7;   \
        *(int4*)&A_lds[r8][c8]   = areg8;  *(int4*)&A_lds[r9][c9]   = areg9;   \
        *(int4*)&A_lds[r10][c10] = areg10; *(int4*)&A_lds[r11][c11] = areg11;  \
    }

    f32x4 acc[12] = {};
    float bs[4][8];

#define LOADB(dst, t_) { const float* bp = bbase + (size_t)(t_) * 32 * N;      \
        _Pragma("unroll") for (int j = 0; j < 8; ++j) dst[j] = bp[(size_t)j * N]; }
#define PACKB(fr, sv) { _Pragma("unroll") for (int j = 0; j < 8; ++j)          \
        ((unsigned short*)&fr)[j] = f2b(sv[j]); }

    LOADA(0); WRITEA();
    #pragma unroll
    for (int p = 0; p < 4; ++p) LOADB(bs[p], p);
    __syncthreads();

    for (int s = 0; s < 8; ++s) {
        if (s < 7) LOADA(s + 1);
        #pragma unroll
        for (int p = 0; p < 4; ++p) {
            int P = s*4 + p;
            bf16x8 fr;
            PACKB(fr, bs[p]);
            if (P + 4 < 32) LOADB(bs[p], P + 4);
            #pragma unroll
            for (int mf = 0; mf < 12; ++mf) {
                bf16x8 af = *(const bf16x8*)&A_lds[mf*16 + l16][p*32 + g*8];
                acc[mf] = __builtin_amdgcn_mfma_f32_16x16x32_bf16(af, fr, acc[mf], 0, 0, 0);
            }
        }
        if (s < 7) {
            __syncthreads();
            WRITEA();
            __syncthreads();
        }
    }
#undef LOADA
#undef WRITEA
#undef LOADB
#undef PACKB
    if (col < N) {
        #pragma unroll
        for (int mf = 0; mf < 12; ++mf)
            #pragma unroll
            for (int r = 0; r < 4; ++r)
                C[(size_t)(mf * 16 + g * 4 + r) * N + col] = acc[mf][r];
    }
}

// ---------------------------------------------------------------------------
// Fully fused attention per (b,h,half): edge prefix in-block, prep + scores +
// softmax + PV. 256 blocks, 512 thr. Q rows batch-prefetched.
__global__ __launch_bounds__(512) void k_attn(const float* __restrict__ Qb,
        const float* __restrict__ Kg, const float* __restrict__ Vg,
        const int* __restrict__ et, const float* __restrict__ rel,
        const int* __restrict__ mask, float* __restrict__ out)
{
    int bid = blockIdx.x;
    int is = bid & 1;
    int h  = (bid >> 1) & (HH-1);
    int b  = bid >> 5;
    int lo = is * (TT/2);
    __shared__ float K_sh[DH][TT+1];
    __shared__ float V_sh[TT][DH];
    __shared__ uint2 cnt_sh[TT/2][TT];
    __shared__ __align__(16) unsigned char un_raw[6400];
    float (*rel_sh)[DH] = (float(*)[DH])un_raw;
    float (*a_row)[DH]  = (float(*)[DH])(un_raw + 2048);
    float (*p_row)[TT]  = (float(*)[TT])(un_raw + 4096);
    unsigned char* e_sh = un_raw;
    int tid = threadIdx.x;
    int lane = tid & 63, w = tid >> 6;

    for (int idx = tid; idx < TT*16; idx += 512) {
        int r = idx >> 4, q4 = (idx & 15) * 4;
        size_t goff = ((size_t)(b*TT + r))*DD + h*DH + q4;
        float4 kv = *(const float4*)&Kg[goff];
        K_sh[q4  ][r] = kv.x; K_sh[q4+1][r] = kv.y;
        K_sh[q4+2][r] = kv.z; K_sh[q4+3][r] = kv.w;
        float4 vv = *(const float4*)&Vg[goff];
        *(float4*)&V_sh[r][q4] = vv;
    }
    for (int idx = tid; idx < (TT*TT)/4; idx += 512) {
        int4 v = ((const int4*)(et + (size_t)b*TT*TT))[idx];
        unsigned pk = (unsigned)v.x | ((unsigned)v.y << 8) | ((unsigned)v.z << 16) | ((unsigned)v.w << 24);
        *(unsigned*)&e_sh[idx*4] = pk;
    }
    __syncthreads();
    if (tid < TT) {
        unsigned lo32 = 0, hi32 = 0;
        int iend = lo + TT/2;
        for (int i = 0; i < iend; ++i) {
            int r = e_sh[i*TT + tid];
            if (r < 4) lo32 += 1u << (8*r); else hi32 += 1u << (8*(r-4));
            if (i >= lo) cnt_sh[i - lo][tid] = make_uint2(lo32, hi32);
        }
    }
    __syncthreads();
    if (tid < 128) {
        int r = tid >> 4, q4 = (tid & 15) * 4;
        *(float4*)&rel_sh[r][q4] = *(const float4*)&rel[r*DD + h*DH + q4];
    }
    __syncthreads();

    auto processRow = [&](float q, int ii) {
        int i = lo + ii;
        size_t rowoff = (size_t)(b*TT + i);
        float crd[8]; dec8(cnt_sh[ii][i], crd);
        float a = q;
        #pragma unroll
        for (int r = 0; r < 8; ++r) a += crd[r]*rel_sh[r][lane];
        a_row[w][lane] = a;
        float arr[8];
        #pragma unroll
        for (int r = 0; r < 8; ++r) {
            float pr = a * rel_sh[r][lane];
            #pragma unroll
            for (int off = 32; off; off >>= 1) pr += __shfl_xor(pr, off);
            arr[r] = pr;
        }
        float s1;
        {
            int t = lane;
            float s = 0.0f;
            #pragma unroll
            for (int d0 = 0; d0 < DH; d0 += 4) {
                float4 av = *(const float4*)&a_row[w][d0];
                s += av.x*K_sh[d0][t] + av.y*K_sh[d0+1][t]
                   + av.z*K_sh[d0+2][t] + av.w*K_sh[d0+3][t];
            }
            float cr2[8]; dec8(cnt_sh[ii][t], cr2);
            float s2v = cr2[0]*arr[0] + cr2[1]*arr[1] + cr2[2]*arr[2] + cr2[3]*arr[3]
                      + cr2[4]*arr[4] + cr2[5]*arr[5] + cr2[6]*arr[6] + cr2[7]*arr[7];
            int m = mask[rowoff*TT + t];
            s1 = (m == 0) ? -1e9f : (s + s2v)*0.125f;
        }
        float s2 = -1e30f;
        if (lane < TT - DH) {
            int t = DH + lane;
            float s = 0.0f;
            #pragma unroll
            for (int d0 = 0; d0 < DH; d0 += 4) {
                float4 av = *(const float4*)&a_row[w][d0];
                s += av.x*K_sh[d0][t] + av.y*K_sh[d0+1][t]
                   + av.z*K_sh[d0+2][t] + av.w*K_sh[d0+3][t];
            }
            float cr2[8]; dec8(cnt_sh[ii][t], cr2);
            float s2v = cr2[0]*arr[0] + cr2[1]*arr[1] + cr2[2]*arr[2] + cr2[3]*arr[3]
                      + cr2[4]*arr[4] + cr2[5]*arr[5] + cr2[6]*arr[6] + cr2[7]*arr[7];
            int m = mask[rowoff*TT + t];
            s2 = (m == 0) ? -1e9f : (s + s2v)*0.125f;
        }
        float mx = fmaxf(s1, s2);
        #pragma unroll
        for (int off = 32; off; off >>= 1) mx = fmaxf(mx, __shfl_xor(mx, off));
        float e1 = __expf(s1 - mx);
        float e2 = (lane < TT - DH) ? __expf(s2 - mx) : 0.0f;
        float sm = e1 + e2;
        #pragma unroll
        for (int off = 32; off; off >>= 1) sm += __shfl_xor(sm, off);
        float inv = 1.0f / sm;
        p_row[w][lane] = e1 * inv;
        if (lane < TT - DH) p_row[w][DH + lane] = e2 * inv;
        float o = 0.0f;
        #pragma unroll 8
        for (int t = 0; t < TT; ++t) o += p_row[w][t] * V_sh[t][lane];
        out[rowoff*DD + h*DH + lane] = o;
    };

    float qv0, qv1, qv2, qv3, qv4 = 0.0f;
    {
        size_t base = ((size_t)(b*TT + lo + w))*DD + h*DH + lane;
        qv0 = Qb[base];
        qv1 = Qb[base + (size_t)8*DD];
        qv2 = Qb[base + (size_t)16*DD];
        qv3 = Qb[base + (size_t)24*DD];
        if (w < 4) qv4 = Qb[base + (size_t)32*DD];
    }
    processRow(qv0, w);
    processRow(qv1, w + 8);
    processRow(qv2, w + 16);
    processRow(qv3, w + 24);
    if (w < 4) processRow(qv4, w + 32);
}

// ---------------------------------------------------------------------------
// strategy (8) and emotion (6) logits
__global__ __launch_bounds__(256) void k_logits(const float* __restrict__ outs,
        const float* __restrict__ strW, const float* __restrict__ strB,
        const float* __restrict__ emoW, const float* __restrict__ emoB,
        float* __restrict__ o_str, float* __restrict__ o_emo_log)
{
    __shared__ float part[14][16];
    int bid = blockIdx.x; int b = bid / UU, u = bid % UU;
    const float* st = outs + ((size_t)(b*TT + 3*u + 1))*DD;
    const float* em = st + DD;
    int t = threadIdx.x;
    if (t < 224) {
        int o = t >> 4, c = t & 15;
        float s = 0.0f;
        if (o < 8) {
            for (int d = c*64; d < c*64 + 64; ++d) s += st[d]*strW[d*8 + o];
        } else {
            int j = o - 8;
            for (int d = c*64; d < c*64 + 64; ++d) s += em[d]*emoW[d*6 + j];
        }
        part[o][c] = s;
    }
    __syncthreads();
    if (t < 14) {
        float s = 0.0f;
        #pragma unroll
        for (int c2 = 0; c2 < 16; ++c2) s += part[t][c2];
        if (t < 8) o_str[(b*UU + u)*8 + t] = s + strB[t];
        else       o_emo_log[(b*UU + u)*6 + (t-8)] = s + emoB[t-8];
    }
}

// ---------------------------------------------------------------------------
extern "C" void kernel_launch(void* const* d_in, const int* in_sizes, int n_in,
                              void* d_out, int out_size, void* d_ws, size_t ws_size,
                              hipStream_t stream)
{
    const float* hidden  = (const float*)d_in[0];
    const float* emo_csk = (const float*)d_in[1];
    const float* Wq  = (const float*)d_in[2];
    const float* bq  = (const float*)d_in[3];
    const float* Wk  = (const float*)d_in[4];
    const float* bk  = (const float*)d_in[5];
    const float* Wv  = (const float*)d_in[6];
    const float* bv  = (const float*)d_in[7];
    const float* rel = (const float*)d_in[8];
    const float* fusW = (const float*)d_in[9];
    const float* fusB = (const float*)d_in[10];
    const float* bng = (const float*)d_in[11];
    const float* bnb = (const float*)d_in[12];
    const float* bnm = (const float*)d_in[13];
    const float* bnv = (const float*)d_in[14];
    const float* cskW = (const float*)d_in[15];
    const float* cskB = (const float*)d_in[16];
    const float* emoW = (const float*)d_in[17];
    const float* emoB = (const float*)d_in[18];
    const float* strW = (const float*)d_in[19];
    const float* strB = (const float*)d_in[20];
    const float* bowW = (const float*)d_in[21];
    const int* clsIdx = (const int*)d_in[22];
    const int* tGraph = (const int*)d_in[23];
    const int* iGraph = (const int*)d_in[24];
    const int* tEdge  = (const int*)d_in[25];
    const int* iEdge  = (const int*)d_in[26];

    float* out = (float*)d_out;
    float* o_last_stra  = out;             // B*D          = 8192
    float* o_emo_trans  = out + 8192;      // B*U*D        = 196608
    float* o_last_delta = out + 204800;    // B*D          = 8192
    float* o_sem_cls    = out + 212992;    // B*U*D        = 196608
    float* o_str_log    = out + 409600;    // B*U*8        = 1536
    float* o_emo_log    = out + 411136;    // B*U*6        = 1152
    float* o_bow        = out + 412288;    // B*U*VOCAB

    float* ws = (float*)d_ws;
    const int SZ_BTD = BB*TT*DD;   // 589824
    const int SZ_BUD = BB*UU*DD;   // 196608
    float* trans_in  = ws;
    float* Qb        = trans_in + SZ_BTD;
    float* Kb        = Qb + SZ_BTD;
    float* Vb        = Kb + SZ_BTD;
    float* trans_out = Vb + SZ_BTD;
    float* inter_out = trans_out + SZ_BTD;
    float* outsB     = inter_out + SZ_BTD;
    float* csk_norm  = outsB + SZ_BTD;
    unsigned short* deltaB = (unsigned short*)(csk_norm + SZ_BUD);

    // 1. gather cls + batchnorm (merged, grid-split)
    k_gather_bn<<<dim3(BB*UU + (BB*UU*CSKN+255)/256), dim3(256), 0, stream>>>(
            hidden, clsIdx, o_sem_cls, trans_in, emo_csk, bng, bnb, bnm, bnv, csk_norm);
    // 2. csk_proj GEMM fused with scatter-add into trans_in[:,2::3]
    mm64<4><<<dim3(16, 3), dim3(256), 0, stream>>>(csk_norm, nullptr, CSKN, cskW, cskB,
            nullptr, nullptr, trans_in, DD, CSKN, nullptr, nullptr, nullptr, nullptr, nullptr);

    auto attention = [&](const float* x, const int* graph, const int* edge, float* ctx_out) {
        mm_qkv<<<dim3(48, (BB*TT)/64), dim3(256), 0, stream>>>(x, Wq, Wk, Wv, bq, bk, bv, Qb, Kb, Vb);
        k_attn<<<dim3(BB*HH*2), dim3(512), 0, stream>>>(Qb, Kb, Vb, edge, rel, graph, ctx_out);
    };
    attention(trans_in, tGraph, tEdge, trans_out);
    attention(trans_out, iGraph, iEdge, inter_out);

    // fusion gate + blend + ALL elementwise output splits (EPI=5)
    mm64<5><<<dim3(16, (BB*TT)/64), dim3(256), 0, stream>>>(trans_out, inter_out, DD, fusW, fusB,
            trans_out, inter_out, outsB, DD, 2*DD,
            o_sem_cls, deltaB, o_emo_trans, o_last_stra, o_last_delta);

    // strategy/emotion logits
    k_logits<<<dim3(BB*UU), dim3(256), 0, stream>>>(outsB, strW, strB, emoW, emoB,
            o_str_log, o_emo_log);

    // bow_logits = delta @ bow_W (R11 barrier-amortized variant, session best)
    mm_bow<<<dim3((NVOCAB+63)/64), dim3(256), 0, stream>>>(deltaB, bowW, o_bow);
}